// Round 12
// baseline (443.834 us; speedup 1.0000x reference)
//
#include <hip/hip_runtime.h>
#include <hip/hip_bf16.h>

#define NN 20000
#define NE 320000
#define DD 256

typedef __attribute__((ext_vector_type(8))) short bf16x8;   // 8 bf16 = 4 VGPR (MFMA A/B frag)
typedef __attribute__((ext_vector_type(4))) float f32x4;    // MFMA C/D frag
typedef __attribute__((ext_vector_type(4))) int   int4v;    // 16B chunk
typedef __attribute__((ext_vector_type(4))) float float4v;

typedef __attribute__((address_space(1))) unsigned int gas_uint;
typedef __attribute__((address_space(3))) unsigned int las_uint;
static __device__ __forceinline__ void gload16(const void* g, void* l) {
    __builtin_amdgcn_global_load_lds((gas_uint*)g, (las_uint*)l, 16, 0, 0);
}

// raw barrier (no implicit vmcnt(0) drain) + counted vmem waits; both are IR memory fences
#define SBAR()   asm volatile("s_barrier" ::: "memory")
#define WAITV(N) asm volatile("s_waitcnt vmcnt(" #N ")" ::: "memory")

__device__ __forceinline__ unsigned short f2bf(float f) {
    union { float f; unsigned u; } v; v.f = f;
    unsigned r = v.u + 0x7fffu + ((v.u >> 16) & 1u);   // RNE
    return (unsigned short)(r >> 16);
}
__device__ __forceinline__ float bf2f(unsigned short h) {
    union { unsigned u; float f; } v; v.u = ((unsigned)h) << 16;
    return v.f;
}
__device__ __forceinline__ float fast_sigmoid(float x) {
    return 1.f / (1.f + __expf(-x));                   // inf-safe: 1/(1+inf)=0
}
__device__ __forceinline__ float fast_tanh(float x) {
    x = fminf(fmaxf(x, -30.f), 30.f);                  // clamp: avoid inf/inf NaN
    float e = __expf(-2.f * x);
    return (1.f - e) / (1.f + e);
}

// ---------------- prologue kernels ----------------

__global__ void cast_kernel(const float* __restrict__ in, unsigned short* __restrict__ out, int n) {
    int i = (blockIdx.x * blockDim.x + threadIdx.x) * 4;
    if (i >= n) return;
    float4v v = *reinterpret_cast<const float4v*>(in + i);
    uint2 o;
    o.x = (unsigned)f2bf(v.x) | ((unsigned)f2bf(v.y) << 16);
    o.y = (unsigned)f2bf(v.z) | ((unsigned)f2bf(v.w) << 16);
    *reinterpret_cast<uint2*>(out + i) = o;
}

// P_all = W_all @ Wih^T : A [1280][256] bf16 (natural W layout), Bt [768][256] bf16,
// C [1280][768] bf16. BM=128,BN=64,BK=64; single-buffer m97 loop (one-off tiny GEMM).
__global__ __launch_bounds__(256) void pgemm_kernel(const unsigned short* __restrict__ A,
                                                    const unsigned short* __restrict__ Bt,
                                                    unsigned short* __restrict__ C) {
    __shared__ __align__(16) unsigned short As[128 * 64];
    __shared__ __align__(16) unsigned short Bs[64 * 64];
    const int t = threadIdx.x;
    const int lane = t & 63;
    const int w = t >> 6;
    const int wr = w >> 1, wc = w & 1;
    const int m0 = blockIdx.y * 128;
    const int n0 = blockIdx.x * 64;

    f32x4 acc[4][2];
    const f32x4 z4 = {0.f, 0.f, 0.f, 0.f};
    for (int i = 0; i < 4; ++i) for (int j = 0; j < 2; ++j) acc[i][j] = z4;

    for (int kt = 0; kt < 4; ++kt) {
        const int k0 = kt * 64;
#pragma unroll
        for (int rnd = 0; rnd < 4; ++rnd) {            // A: 1024 chunks
            int cb = rnd * 256 + (w << 6);
            int c = cb + lane;
            int row = c >> 3, sl = c & 7;
            int gsl = sl ^ (row & 7);
            gload16(A + (size_t)(m0 + row) * 256 + k0 + gsl * 8, &As[cb * 8]);
        }
#pragma unroll
        for (int rnd = 0; rnd < 2; ++rnd) {            // B: 512 chunks
            int cb = rnd * 256 + (w << 6);
            int c = cb + lane;
            int row = c >> 3, sl = c & 7;
            int gsl = sl ^ (row & 7);
            gload16(Bt + (size_t)(n0 + row) * 256 + k0 + gsl * 8, &Bs[cb * 8]);
        }
        __syncthreads();
#pragma unroll
        for (int ks = 0; ks < 2; ++ks) {
            const int slot = ks * 4 + (lane >> 4);
            bf16x8 a[4], b[2];
#pragma unroll
            for (int mi = 0; mi < 4; ++mi) {
                int row = wr * 64 + mi * 16 + (lane & 15);
                a[mi] = *reinterpret_cast<const bf16x8*>(&As[row * 64 + ((slot ^ (row & 7)) << 3)]);
            }
#pragma unroll
            for (int ni = 0; ni < 2; ++ni) {
                int row = wc * 32 + ni * 16 + (lane & 15);
                b[ni] = *reinterpret_cast<const bf16x8*>(&Bs[row * 64 + ((slot ^ (row & 7)) << 3)]);
            }
#pragma unroll
            for (int mi = 0; mi < 4; ++mi)
#pragma unroll
                for (int ni = 0; ni < 2; ++ni)
                    acc[mi][ni] = __builtin_amdgcn_mfma_f32_16x16x32_bf16(a[mi], b[ni], acc[mi][ni], 0, 0, 0);
        }
        __syncthreads();
    }
#pragma unroll
    for (int mi = 0; mi < 4; ++mi)
#pragma unroll
        for (int ni = 0; ni < 2; ++ni)
#pragma unroll
            for (int r = 0; r < 4; ++r) {
                int grow = m0 + wr * 64 + mi * 16 + (lane >> 4) * 4 + r;
                int gcol = n0 + wc * 32 + ni * 16 + (lane & 15);
                C[(size_t)grow * 768 + gcol] = f2bf(acc[mi][ni][r]);
            }
}

// 4-gate combined weight (R3 layout, built from fused P): Wc45[l][np][k],
// np = (d>>4)*64 + g*16 + (d&15), k in [0,512). Gate g: 0=r, 1=z, 2=i_n, 3=h_n.
// k<256 (agg-half): g in {r,z,i_n} from P_l[k][gate_row], h_n row = 0.
// k>=256 (h-half):  g in {r,z,h_n} from Whh[gate_row][k-256], i_n row = 0.
__global__ void wc4_kernel(const unsigned short* __restrict__ Pall,
                           const float* __restrict__ whh,
                           unsigned short* __restrict__ Wc45) {
    int id = blockIdx.x * 256 + threadIdx.x;          // 5*1024*512 = 2621440
    int l = id >> 19;
    int rem = id & 524287;
    int np = rem >> 9, k = rem & 511;
    int g = (np >> 4) & 3;
    int d = ((np >> 6) << 4) | (np & 15);
    unsigned short v;
    if (k < 256) {
        if (g == 3) v = 0;
        else {
            int gate_row = (g == 2 ? 512 : g * 256) + d;
            v = Pall[((size_t)(l * 256 + k)) * 768 + gate_row];
        }
    } else {
        if (g == 2) v = 0;
        else {
            int gate_row = (g == 3 ? 512 : g * 256) + d;
            v = f2bf(whh[(size_t)gate_row * 256 + (k - 256)]);
        }
    }
    Wc45[id] = v;
}

// ---------------- CSR build (once per launch) ----------------

__global__ void hist_kernel(const int* __restrict__ dst, int* __restrict__ deg) {
    int e = blockIdx.x * 256 + threadIdx.x;
    if (e < NE) atomicAdd(&deg[dst[e]], 1);
}

__global__ __launch_bounds__(1024) void scan_kernel(const int* __restrict__ deg, int* __restrict__ base) {
    __shared__ int part[1024];
    const int t = threadIdx.x;
    const int CH = 20;
    int start = t * CH;
    int s = 0;
    for (int i = 0; i < CH; ++i) { int idx = start + i; if (idx < NN) s += deg[idx]; }
    part[t] = s; __syncthreads();
    for (int off = 1; off < 1024; off <<= 1) {
        int v = (t >= off) ? part[t - off] : 0;
        __syncthreads();
        part[t] += v;
        __syncthreads();
    }
    int run = (t == 0) ? 0 : part[t - 1];
    for (int i = 0; i < CH; ++i) {
        int idx = start + i;
        if (idx < NN) { base[idx] = run; run += deg[idx]; }
    }
    if (t == 1023) base[NN] = run;
}

__global__ void fill_kernel(const int* __restrict__ src, const int* __restrict__ dst,
                            const float* __restrict__ attr, const int* __restrict__ base,
                            int* __restrict__ cursor, int* __restrict__ ssrc,
                            float* __restrict__ sattr) {
    int e = blockIdx.x * 256 + threadIdx.x;
    if (e >= NE) return;
    int d = dst[e];
    int pos = base[d] + atomicAdd(&cursor[d], 1);
    ssrc[pos] = src[e];
    sattr[pos] = attr[e];
}

// ---------------- aggregation: 4 edges in flight (quarter-waves, 32B/lane/edge) ----------
__global__ __launch_bounds__(256) void gather_agg_kernel(const unsigned short* __restrict__ Hbf,
                                                         const int* __restrict__ base,
                                                         const int* __restrict__ ssrc,
                                                         const float* __restrict__ sattr,
                                                         unsigned short* __restrict__ AggBf) {
    int node = blockIdx.x * 4 + (threadIdx.x >> 6);
    if (node >= NN) return;
    int lane = threadIdx.x & 63;
    int q = lane >> 4;                                 // quarter 0..3 -> edge p = b0+q, stride 4
    int ql = lane & 15;                                // channels ql*16 .. ql*16+15
    int b0 = base[node], b1 = base[node + 1];
    float ac[16];
#pragma unroll
    for (int j = 0; j < 16; ++j) ac[j] = 0.f;
    for (int p = b0 + q; p < b1; p += 4) {
        int s = ssrc[p];
        float a = sattr[p];
        const unsigned short* rowp = Hbf + (size_t)s * 256 + ql * 16;
        int4v v0 = *reinterpret_cast<const int4v*>(rowp);
        int4v v1 = *reinterpret_cast<const int4v*>(rowp + 8);
#pragma unroll
        for (int j = 0; j < 4; ++j) {
            unsigned u0 = (unsigned)v0[j];
            ac[2 * j]     += a * bf2f((unsigned short)(u0 & 0xffff));
            ac[2 * j + 1] += a * bf2f((unsigned short)(u0 >> 16));
            unsigned u1 = (unsigned)v1[j];
            ac[8 + 2 * j]     += a * bf2f((unsigned short)(u1 & 0xffff));
            ac[8 + 2 * j + 1] += a * bf2f((unsigned short)(u1 >> 16));
        }
    }
#pragma unroll
    for (int j = 0; j < 16; ++j) {
        ac[j] += __shfl_xor(ac[j], 16);
        ac[j] += __shfl_xor(ac[j], 32);
    }
    if (q == 0) {
        unsigned ou[8];
#pragma unroll
        for (int j = 0; j < 8; ++j)
            ou[j] = (unsigned)f2bf(ac[2 * j]) | ((unsigned)f2bf(ac[2 * j + 1]) << 16);
        unsigned short* op = AggBf + (size_t)node * 256 + ql * 16;
        *reinterpret_cast<int4v*>(op)     = *reinterpret_cast<int4v*>(&ou[0]);
        *reinterpret_cast<int4v*>(op + 8) = *reinterpret_cast<int4v*>(&ou[4]);
    }
}

// ---------------- gru7: fine-phase counted-vmcnt pipeline (T3+T4+T5 port) ----------------
// GEMM C = [agg|h] (M x K512) @ Wc4^T (1024 x 512), 4-gate layout (gates = n-frags).
// Tile 192(M) x 256(N), 8 waves 2M x 4N, wave tile 96x64, acc[6][4] = 96 VGPR.
// LDS 112KB: double-buffered K-tiles (A 192x64 + B 256x64 per buf).
// Window kt: bulk-issue kt+1's 7 gload16 into dead buffer, WAITV(7) (kt's done, kt+1
// stays IN FLIGHT across barriers - never drain-0 mid-loop), then 4 fine phases:
// {7 ds_read -> SBAR -> setprio(1) -> 12 MFMA -> setprio(0) -> SBAR}.
// Grid 420 = 105 m-tiles x 4 n-tiles, bijective m204 XCD swizzle (q=52, r=4).
__global__ __launch_bounds__(512) void gru7_kernel(const unsigned short* __restrict__ Abf,
                                                   const unsigned short* __restrict__ Hbf,
                                                   const unsigned short* __restrict__ Wc4,
                                                   const float* __restrict__ b_ih,
                                                   const float* __restrict__ b_hh,
                                                   const float* __restrict__ x_f32,
                                                   float* __restrict__ h_out,
                                                   unsigned short* __restrict__ Hbf_out,
                                                   int first, int last) {
    __shared__ __align__(16) unsigned short As[2][192 * 64];   // 48 KB
    __shared__ __align__(16) unsigned short Bs[2][256 * 64];   // 64 KB
    const int t = threadIdx.x;
    const int lane = t & 63;
    const int w = t >> 6;                              // 0..7
    const int wm = w >> 2, wn = w & 3;                 // 2M x 4N
    // bijective XCD swizzle (m204): nwg=420, q=52, r=4
    int b = blockIdx.x;
    int xcd = b & 7, loc = b >> 3;
    int ww = (xcd < 4 ? xcd * 53 : 4 * 53 + (xcd - 4) * 52) + loc;
    const int nt = ww & 3, mt = ww >> 2;               // nt fast -> A-panel L2 reuse per XCD
    const int m0 = mt * 192;
    const int n0 = nt * 256;

    f32x4 acc[6][4];
    const f32x4 z4 = {0.f, 0.f, 0.f, 0.f};
#pragma unroll
    for (int i = 0; i < 6; ++i)
#pragma unroll
        for (int j = 0; j < 4; ++j) acc[i][j] = z4;

    auto stage = [&](int buf, int kt) {                // 7 gload16 per thread
        const unsigned short* aptr = (kt < 4) ? Abf : Hbf;
        const int ka = (kt & 3) * 64;
        const int kb = kt * 64;
#pragma unroll
        for (int rnd = 0; rnd < 3; ++rnd) {            // A: 1536 chunks (192 rows x 8 slots)
            int c = rnd * 512 + t;
            int row = c >> 3, sl = c & 7;
            int gsl = sl ^ (row & 7);                  // pre-swizzled global src, linear LDS dest
            gload16(aptr + (size_t)(m0 + row) * 256 + ka + gsl * 8, &As[buf][c * 8]);
        }
#pragma unroll
        for (int rnd = 0; rnd < 4; ++rnd) {            // B: 2048 chunks (256 rows x 8 slots)
            int c = rnd * 512 + t;
            int row = c >> 3, sl = c & 7;
            int gsl = sl ^ (row & 7);
            gload16(Wc4 + (size_t)(n0 + row) * 512 + kb + gsl * 8, &Bs[buf][c * 8]);
        }
    };

    stage(0, 0);
    for (int kt = 0; kt < 8; ++kt) {
        const int cur = kt & 1;
        if (kt < 7) {
            stage(cur ^ 1, kt + 1);                    // into dead buffer (all reads done at
            WAITV(7);                                  //   prior window's trailing barrier)
        } else {
            WAITV(0);                                  // last window: nothing to preserve
        }
        SBAR();                                        // kt's data published to all waves
#pragma unroll
        for (int ph = 0; ph < 4; ++ph) {
            const int ks = ph >> 1, mh = ph & 1;       // quadrant: k-slice x m-frag-half
            const int slot = ks * 4 + (lane >> 4);
            bf16x8 a[3], bb[4];
#pragma unroll
            for (int j = 0; j < 3; ++j) {
                int arow = wm * 96 + (mh * 3 + j) * 16 + (lane & 15);
                a[j] = *reinterpret_cast<const bf16x8*>(&As[cur][arow * 64 + ((slot ^ (arow & 7)) << 3)]);
            }
#pragma unroll
            for (int ni = 0; ni < 4; ++ni) {
                int brow = wn * 64 + ni * 16 + (lane & 15);
                bb[ni] = *reinterpret_cast<const bf16x8*>(&Bs[cur][brow * 64 + ((slot ^ (brow & 7)) << 3)]);
            }
            SBAR();                                    // phase-entry lockstep (role-split)
            __builtin_amdgcn_s_setprio(1);
#pragma unroll
            for (int j = 0; j < 3; ++j)
#pragma unroll
                for (int ni = 0; ni < 4; ++ni)
                    acc[mh * 3 + j][ni] = __builtin_amdgcn_mfma_f32_16x16x32_bf16(a[j], bb[ni], acc[mh * 3 + j][ni], 0, 0, 0);
            __builtin_amdgcn_s_setprio(0);
            SBAR();                                    // phase-exit
        }
    }

    // ---- fused GRU gate epilogue: acc[mi][g] = gates r,z,i_n,h_n for channel d ----
    const int cc = lane & 15;
    const int d = (nt * 4 + wn) * 16 + cc;             // output channel 0..255
    const float bir = b_ih[d],        bhr = b_hh[d];
    const float biz = b_ih[256 + d],  bhz = b_hh[256 + d];
    const float bin_ = b_ih[512 + d], bhn = b_hh[512 + d];
#pragma unroll
    for (int mi = 0; mi < 6; ++mi)
#pragma unroll
        for (int r = 0; r < 4; ++r) {
            int grow = m0 + wm * 96 + mi * 16 + (lane >> 4) * 4 + r;
            if (grow >= NN) continue;
            size_t idx = (size_t)grow * 256 + d;
            float rr = fast_sigmoid(acc[mi][0][r] + bir + bhr);
            float zz = fast_sigmoid(acc[mi][1][r] + biz + bhz);
            float nn = fast_tanh(acc[mi][2][r] + bin_ + rr * (acc[mi][3][r] + bhn));
            float hp = first ? x_f32[idx] : bf2f(Hbf[idx]);   // bf16 h-carry for l>=1
            float hv = (1.f - zz) * nn + zz * hp;
            if (last) h_out[idx] = hv;
            Hbf_out[idx] = f2bf(hv);
        }
}

// ---------------- launch ----------------

extern "C" void kernel_launch(void* const* d_in, const int* in_sizes, int n_in,
                              void* d_out, int out_size, void* d_ws, size_t ws_size,
                              hipStream_t stream) {
    const float* x     = (const float*)d_in[0];
    const int*   eidx  = (const int*)d_in[1];
    const float* eattr = (const float*)d_in[2];
    const float* W     = (const float*)d_in[3];
    const float* wih   = (const float*)d_in[4];
    const float* whh   = (const float*)d_in[5];
    const float* bih   = (const float*)d_in[6];
    const float* bhh   = (const float*)d_in[7];
    float* out = (float*)d_out;
    const int* esrc = eidx;
    const int* edst = eidx + NE;

    char* p = (char*)d_ws;
    auto alloc = [&](size_t bytes) -> char* {
        char* r = p; p += (bytes + 255) & ~(size_t)255; return r;
    };
    unsigned short* hbfA  = (unsigned short*)alloc((size_t)NN * DD * 2);
    unsigned short* hbfB  = (unsigned short*)alloc((size_t)NN * DD * 2);
    unsigned short* aggbf = (unsigned short*)alloc((size_t)NN * DD * 2);
    unsigned short* wnb   = (unsigned short*)alloc((size_t)5 * DD * DD * 2);   // W natural, bf16
    unsigned short* wihb  = (unsigned short*)alloc((size_t)768 * DD * 2);      // Wih natural, bf16
    unsigned short* pall  = (unsigned short*)alloc((size_t)1280 * 768 * 2);    // P = W @ Wih^T
    unsigned short* wc45  = (unsigned short*)alloc((size_t)5 * 1024 * 512 * 2);
    int*   deg    = (int*)alloc((size_t)NN * 4);
    int*   basep  = (int*)alloc((size_t)(NN + 1) * 4);
    int*   cursor = (int*)alloc((size_t)NN * 4);
    int*   ssrc   = (int*)alloc((size_t)NE * 4);
    float* sattr  = (float*)alloc((size_t)NE * 4);
    alloc(262144);  // guard slack: padded tile rows (20000..20159) read in-workspace garbage

    hipMemsetAsync(deg, 0, (size_t)NN * 4, stream);
    hipMemsetAsync(cursor, 0, (size_t)NN * 4, stream);

    cast_kernel<<<320, 256, 0, stream>>>(W, wnb, 5 * DD * DD);
    cast_kernel<<<192, 256, 0, stream>>>(wih, wihb, 768 * DD);
    cast_kernel<<<5000, 256, 0, stream>>>(x, hbfA, NN * DD);
    pgemm_kernel<<<dim3(12, 10), 256, 0, stream>>>(wnb, wihb, pall);
    wc4_kernel<<<10240, 256, 0, stream>>>(pall, whh, wc45);
    hist_kernel<<<1250, 256, 0, stream>>>(edst, deg);
    scan_kernel<<<1, 1024, 0, stream>>>(deg, basep);
    fill_kernel<<<1250, 256, 0, stream>>>(esrc, edst, eattr, basep, cursor, ssrc, sattr);

    unsigned short* hb_cur = hbfA;
    unsigned short* hb_nxt = hbfB;
    for (int l = 0; l < 5; ++l) {
        gather_agg_kernel<<<5000, 256, 0, stream>>>(hb_cur, basep, ssrc, sattr, aggbf);
        gru7_kernel<<<420, 512, 0, stream>>>(aggbf, hb_cur, wc45 + (size_t)l * 1024 * 512,
                                             bih, bhh, x, out, hb_nxt,
                                             (l == 0) ? 1 : 0, (l == 4) ? 1 : 0);
        unsigned short* tmp = hb_cur; hb_cur = hb_nxt; hb_nxt = tmp;
    }
    (void)in_sizes; (void)n_in; (void)out_size; (void)ws_size;
}

// Round 13
// 343.793 us; speedup vs baseline: 1.2910x; 1.2910x over previous
//
#include <hip/hip_runtime.h>
#include <hip/hip_bf16.h>

#define NN 20000
#define NE 320000
#define DD 256

typedef __attribute__((ext_vector_type(8))) short bf16x8;   // 8 bf16 = 4 VGPR (MFMA A/B frag)
typedef __attribute__((ext_vector_type(4))) float f32x4;    // MFMA C/D frag
typedef __attribute__((ext_vector_type(4))) int   int4v;    // 16B chunk
typedef __attribute__((ext_vector_type(4))) float float4v;

typedef __attribute__((address_space(1))) unsigned int gas_uint;
typedef __attribute__((address_space(3))) unsigned int las_uint;
static __device__ __forceinline__ void gload16(const void* g, void* l) {
    __builtin_amdgcn_global_load_lds((gas_uint*)g, (las_uint*)l, 16, 0, 0);
}

__device__ __forceinline__ unsigned short f2bf(float f) {
    union { float f; unsigned u; } v; v.f = f;
    unsigned r = v.u + 0x7fffu + ((v.u >> 16) & 1u);   // RNE
    return (unsigned short)(r >> 16);
}
__device__ __forceinline__ float bf2f(unsigned short h) {
    union { unsigned u; float f; } v; v.u = ((unsigned)h) << 16;
    return v.f;
}
__device__ __forceinline__ float fast_sigmoid(float x) {
    return 1.f / (1.f + __expf(-x));                   // inf-safe: 1/(1+inf)=0
}
__device__ __forceinline__ float fast_tanh(float x) {
    x = fminf(fmaxf(x, -30.f), 30.f);                  // clamp: avoid inf/inf NaN
    float e = __expf(-2.f * x);
    return (1.f - e) / (1.f + e);
}

// ---------------- fused prologue: casts + Wc5 h-half + hist, one dispatch ----------------
// Section map (blocks of 256):
//   [0, 5000)    cast x -> hbfA (f32->bf16, float4/thread)
//   [5000, 5320) cast W -> wnb
//   [5320, 5512) cast wih -> wihb
//   [5512, 5704) Wc5 h-half from whh: wc5[l*2+1][n3][k] (identical for all l -> 1 read, 5 writes)
//   [5704, 6954) hist: deg[dst[e]]++
__global__ void prep_kernel(const float* __restrict__ x, unsigned short* __restrict__ hbfA,
                            const float* __restrict__ W, unsigned short* __restrict__ wnb,
                            const float* __restrict__ wih, unsigned short* __restrict__ wihb,
                            const float* __restrict__ whh, unsigned short* __restrict__ wc5,
                            const int* __restrict__ edst, int* __restrict__ deg) {
    const int b = blockIdx.x, t = threadIdx.x;
    if (b < 5000) {
        int i = (b * 256 + t) * 4;                    // 5,120,000 floats
        float4v v = *reinterpret_cast<const float4v*>(x + i);
        uint2 o;
        o.x = (unsigned)f2bf(v.x) | ((unsigned)f2bf(v.y) << 16);
        o.y = (unsigned)f2bf(v.z) | ((unsigned)f2bf(v.w) << 16);
        *reinterpret_cast<uint2*>(hbfA + i) = o;
    } else if (b < 5320) {
        int i = ((b - 5000) * 256 + t) * 4;           // 327,680 floats
        float4v v = *reinterpret_cast<const float4v*>(W + i);
        uint2 o;
        o.x = (unsigned)f2bf(v.x) | ((unsigned)f2bf(v.y) << 16);
        o.y = (unsigned)f2bf(v.z) | ((unsigned)f2bf(v.w) << 16);
        *reinterpret_cast<uint2*>(wnb + i) = o;
    } else if (b < 5512) {
        int i = ((b - 5320) * 256 + t) * 4;           // 196,608 floats
        float4v v = *reinterpret_cast<const float4v*>(wih + i);
        uint2 o;
        o.x = (unsigned)f2bf(v.x) | ((unsigned)f2bf(v.y) << 16);
        o.y = (unsigned)f2bf(v.z) | ((unsigned)f2bf(v.w) << 16);
        *reinterpret_cast<uint2*>(wihb + i) = o;
    } else if (b < 5704) {
        int id = (b - 5512) * 256 + t;                // 49,152 = 768 n3 x 64 k-chunks
        int n3 = id >> 6, k0 = (id & 63) * 4;
        int g3 = (n3 >> 4) % 3;
        int d = (n3 / 48) * 16 + (n3 & 15);
        int gr = g3 * 256 + d;                        // g3: 0=r, 1=z, 2=h_n
        float4v v = *reinterpret_cast<const float4v*>(whh + gr * 256 + k0);
        uint2 o;
        o.x = (unsigned)f2bf(v.x) | ((unsigned)f2bf(v.y) << 16);
        o.y = (unsigned)f2bf(v.z) | ((unsigned)f2bf(v.w) << 16);
#pragma unroll
        for (int l = 0; l < 5; ++l)
            *reinterpret_cast<uint2*>(wc5 + ((size_t)(l * 2 + 1) * 768 + n3) * 256 + k0) = o;
    } else {
        int e = (b - 5704) * 256 + t;
        if (e < NE) atomicAdd(&deg[edst[e]], 1);
    }
}

// P = W_all @ Wih^T, epilogue writes DIRECTLY into wc5 agg-half (hf=0) positions.
// A [1280][256] bf16 (natural W layout, rows = l*256+k), Bt [768][256] bf16 (rows = gate_row).
// BM=128,BN=64,BK=64; single-buffer m97 loop (one-off tiny GEMM).
__global__ __launch_bounds__(256) void pgemm_kernel(const unsigned short* __restrict__ A,
                                                    const unsigned short* __restrict__ Bt,
                                                    unsigned short* __restrict__ wc5) {
    __shared__ __align__(16) unsigned short As[128 * 64];
    __shared__ __align__(16) unsigned short Bs[64 * 64];
    const int t = threadIdx.x;
    const int lane = t & 63;
    const int w = t >> 6;
    const int wr = w >> 1, wc = w & 1;
    const int m0 = blockIdx.y * 128;
    const int n0 = blockIdx.x * 64;

    f32x4 acc[4][2];
    const f32x4 z4 = {0.f, 0.f, 0.f, 0.f};
    for (int i = 0; i < 4; ++i) for (int j = 0; j < 2; ++j) acc[i][j] = z4;

    for (int kt = 0; kt < 4; ++kt) {
        const int k0 = kt * 64;
#pragma unroll
        for (int rnd = 0; rnd < 4; ++rnd) {            // A: 1024 chunks
            int cb = rnd * 256 + (w << 6);
            int c = cb + lane;
            int row = c >> 3, sl = c & 7;
            int gsl = sl ^ (row & 7);
            gload16(A + (size_t)(m0 + row) * 256 + k0 + gsl * 8, &As[cb * 8]);
        }
#pragma unroll
        for (int rnd = 0; rnd < 2; ++rnd) {            // B: 512 chunks
            int cb = rnd * 256 + (w << 6);
            int c = cb + lane;
            int row = c >> 3, sl = c & 7;
            int gsl = sl ^ (row & 7);
            gload16(Bt + (size_t)(n0 + row) * 256 + k0 + gsl * 8, &Bs[cb * 8]);
        }
        __syncthreads();
#pragma unroll
        for (int ks = 0; ks < 2; ++ks) {
            const int slot = ks * 4 + (lane >> 4);
            bf16x8 a[4], b[2];
#pragma unroll
            for (int mi = 0; mi < 4; ++mi) {
                int row = wr * 64 + mi * 16 + (lane & 15);
                a[mi] = *reinterpret_cast<const bf16x8*>(&As[row * 64 + ((slot ^ (row & 7)) << 3)]);
            }
#pragma unroll
            for (int ni = 0; ni < 2; ++ni) {
                int row = wc * 32 + ni * 16 + (lane & 15);
                b[ni] = *reinterpret_cast<const bf16x8*>(&Bs[row * 64 + ((slot ^ (row & 7)) << 3)]);
            }
#pragma unroll
            for (int mi = 0; mi < 4; ++mi)
#pragma unroll
                for (int ni = 0; ni < 2; ++ni)
                    acc[mi][ni] = __builtin_amdgcn_mfma_f32_16x16x32_bf16(a[mi], b[ni], acc[mi][ni], 0, 0, 0);
        }
        __syncthreads();
    }
#pragma unroll
    for (int mi = 0; mi < 4; ++mi)
#pragma unroll
        for (int ni = 0; ni < 2; ++ni)
#pragma unroll
            for (int r = 0; r < 4; ++r) {
                int grow = m0 + wr * 64 + mi * 16 + (lane >> 4) * 4 + r;   // = l*256 + k
                int gcol = n0 + wc * 32 + ni * 16 + (lane & 15);           // = gate_row
                int l = grow >> 8, k = grow & 255;
                int g3 = gcol >> 8, d = gcol & 255;                        // g3: 0=r,1=z,2=i_n
                int n3 = (d >> 4) * 48 + g3 * 16 + (d & 15);
                wc5[((size_t)(l * 2) * 768 + n3) * 256 + k] = f2bf(acc[mi][ni][r]);
            }
}

// ---------------- CSR build ----------------

__global__ __launch_bounds__(1024) void scan_kernel(const int* __restrict__ deg, int* __restrict__ base) {
    __shared__ int part[1024];
    const int t = threadIdx.x;
    const int CH = 20;
    int start = t * CH;
    int s = 0;
    for (int i = 0; i < CH; ++i) { int idx = start + i; if (idx < NN) s += deg[idx]; }
    part[t] = s; __syncthreads();
    for (int off = 1; off < 1024; off <<= 1) {
        int v = (t >= off) ? part[t - off] : 0;
        __syncthreads();
        part[t] += v;
        __syncthreads();
    }
    int run = (t == 0) ? 0 : part[t - 1];
    for (int i = 0; i < CH; ++i) {
        int idx = start + i;
        if (idx < NN) { base[idx] = run; run += deg[idx]; }
    }
    if (t == 1023) base[NN] = run;
}

__global__ void fill_kernel(const int* __restrict__ src, const int* __restrict__ dst,
                            const float* __restrict__ attr, const int* __restrict__ base,
                            int* __restrict__ cursor, int* __restrict__ ssrc,
                            float* __restrict__ sattr) {
    int e = blockIdx.x * 256 + threadIdx.x;
    if (e >= NE) return;
    int d = dst[e];
    int pos = base[d] + atomicAdd(&cursor[d], 1);
    ssrc[pos] = src[e];
    sattr[pos] = attr[e];
}

// ---------------- aggregation: 4 edges in flight (quarter-waves, 32B/lane/edge) ----------
__global__ __launch_bounds__(256) void gather_agg_kernel(const unsigned short* __restrict__ Hbf,
                                                         const int* __restrict__ base,
                                                         const int* __restrict__ ssrc,
                                                         const float* __restrict__ sattr,
                                                         unsigned short* __restrict__ AggBf) {
    int node = blockIdx.x * 4 + (threadIdx.x >> 6);
    if (node >= NN) return;
    int lane = threadIdx.x & 63;
    int q = lane >> 4;                                 // quarter 0..3 -> edge p = b0+q, stride 4
    int ql = lane & 15;                                // channels ql*16 .. ql*16+15
    int b0 = base[node], b1 = base[node + 1];
    float ac[16];
#pragma unroll
    for (int j = 0; j < 16; ++j) ac[j] = 0.f;
    for (int p = b0 + q; p < b1; p += 4) {
        int s = ssrc[p];
        float a = sattr[p];
        const unsigned short* rowp = Hbf + (size_t)s * 256 + ql * 16;
        int4v v0 = *reinterpret_cast<const int4v*>(rowp);
        int4v v1 = *reinterpret_cast<const int4v*>(rowp + 8);
#pragma unroll
        for (int j = 0; j < 4; ++j) {
            unsigned u0 = (unsigned)v0[j];
            ac[2 * j]     += a * bf2f((unsigned short)(u0 & 0xffff));
            ac[2 * j + 1] += a * bf2f((unsigned short)(u0 >> 16));
            unsigned u1 = (unsigned)v1[j];
            ac[8 + 2 * j]     += a * bf2f((unsigned short)(u1 & 0xffff));
            ac[8 + 2 * j + 1] += a * bf2f((unsigned short)(u1 >> 16));
        }
    }
#pragma unroll
    for (int j = 0; j < 16; ++j) {
        ac[j] += __shfl_xor(ac[j], 16);
        ac[j] += __shfl_xor(ac[j], 32);
    }
    if (q == 0) {
        unsigned ou[8];
#pragma unroll
        for (int j = 0; j < 8; ++j)
            ou[j] = (unsigned)f2bf(ac[2 * j]) | ((unsigned)f2bf(ac[2 * j + 1]) << 16);
        unsigned short* op = AggBf + (size_t)node * 256 + ql * 16;
        *reinterpret_cast<int4v*>(op)     = *reinterpret_cast<int4v*>(&ou[0]);
        *reinterpret_cast<int4v*>(op + 8) = *reinterpret_cast<int4v*>(&ou[4]);
    }
}

// ---------------- fused GRU GEMM: 8-wave 3-gate, BM=128, BN=96 (R10's gru4, verbatim) -------
__global__ __launch_bounds__(512) void gru4_kernel(const unsigned short* __restrict__ Abf,
                                                   const unsigned short* __restrict__ Hbf,
                                                   const unsigned short* __restrict__ Wc,
                                                   const float* __restrict__ b_ih,
                                                   const float* __restrict__ b_hh,
                                                   const float* __restrict__ x_f32,
                                                   float* __restrict__ h_out,
                                                   unsigned short* __restrict__ Hbf_out,
                                                   int first, int last) {
    __shared__ __align__(16) unsigned short As[128 * 64];
    __shared__ __align__(16) unsigned short Bs[96 * 64];
    const int t = threadIdx.x;
    const int lane = t & 63;
    const int w = t >> 6;                              // 0..7
    const int wm = w >> 1, wn = w & 1;                 // 4 M-groups x 2 N(dg)-groups
    int b = blockIdx.x;
    int ww = (b & 7) * 158 + (b >> 3);                 // XCD-chunked (1264 = 8*158, exact)
    const int mt = ww >> 3, dgp = ww & 7;              // dgp fast -> A-panel L2 reuse per XCD
    const int m0 = mt * 128;

    f32x4 aR[2], aZ[2], aI[2], aH[2];
    const f32x4 z4 = {0.f, 0.f, 0.f, 0.f};
#pragma unroll
    for (int i = 0; i < 2; ++i) { aR[i] = z4; aZ[i] = z4; aI[i] = z4; aH[i] = z4; }

    auto do_half = [&](const unsigned short* __restrict__ aptr,
                       const unsigned short* __restrict__ wcb,
                       f32x4 (&aX)[2]) {
        for (int kq = 0; kq < 4; ++kq) {
            const int ka = kq * 64;
#pragma unroll
            for (int rnd = 0; rnd < 2; ++rnd) {        // A: 1024 chunks / 512 thr
                int cb = rnd * 512 + (w << 6);
                int c = cb + lane;
                int row = c >> 3, sl = c & 7;
                int gsl = sl ^ (row & 7);              // pre-swizzled global src, linear LDS dest
                gload16(aptr + (size_t)(m0 + row) * 256 + ka + gsl * 8, &As[cb * 8]);
            }
            {                                          // B: chunks 0..511 (rows 0..63)
                int cb = (w << 6);
                int c = cb + lane;
                int row = c >> 3, sl = c & 7;
                int gsl = sl ^ (row & 7);
                gload16(wcb + (size_t)(dgp * 96 + row) * 256 + ka + gsl * 8, &Bs[cb * 8]);
            }
            if (w < 4) {                               // B: chunks 512..767 (rows 64..95)
                int cb = 512 + (w << 6);
                int c = cb + lane;
                int row = c >> 3, sl = c & 7;
                int gsl = sl ^ (row & 7);
                gload16(wcb + (size_t)(dgp * 96 + row) * 256 + ka + gsl * 8, &Bs[cb * 8]);
            }
            __syncthreads();
#pragma unroll
            for (int ks = 0; ks < 2; ++ks) {
                const int slot = ks * 4 + (lane >> 4);
                bf16x8 a[2], bfr[3];
#pragma unroll
                for (int mi = 0; mi < 2; ++mi) {
                    int row = wm * 32 + mi * 16 + (lane & 15);
                    a[mi] = *reinterpret_cast<const bf16x8*>(&As[row * 64 + ((slot ^ (row & 7)) << 3)]);
                }
#pragma unroll
                for (int g3 = 0; g3 < 3; ++g3) {
                    int row = wn * 48 + g3 * 16 + (lane & 15);
                    bfr[g3] = *reinterpret_cast<const bf16x8*>(&Bs[row * 64 + ((slot ^ (row & 7)) << 3)]);
                }
#pragma unroll
                for (int mi = 0; mi < 2; ++mi) {
                    aR[mi] = __builtin_amdgcn_mfma_f32_16x16x32_bf16(a[mi], bfr[0], aR[mi], 0, 0, 0);
                    aZ[mi] = __builtin_amdgcn_mfma_f32_16x16x32_bf16(a[mi], bfr[1], aZ[mi], 0, 0, 0);
                    aX[mi] = __builtin_amdgcn_mfma_f32_16x16x32_bf16(a[mi], bfr[2], aX[mi], 0, 0, 0);
                }
            }
            __syncthreads();
        }
    };

    do_half(Abf, Wc, aI);                              // half 0: gi gates {r,z,i_n}
    do_half(Hbf, Wc + 768 * 256, aH);                  // half 1: gh gates {r,z,h_n}

    // ---- fused GRU gate epilogue ----
    const int d = (dgp * 2 + wn) * 16 + (lane & 15);   // output channel 0..255
    const float bir = b_ih[d],        bhr = b_hh[d];
    const float biz = b_ih[256 + d],  bhz = b_hh[256 + d];
    const float bin_ = b_ih[512 + d], bhn = b_hh[512 + d];
#pragma unroll
    for (int mi = 0; mi < 2; ++mi)
#pragma unroll
        for (int r = 0; r < 4; ++r) {
            int grow = m0 + wm * 32 + mi * 16 + (lane >> 4) * 4 + r;
            if (grow >= NN) continue;
            size_t idx = (size_t)grow * 256 + d;
            float rr = fast_sigmoid(aR[mi][r] + bir + bhr);
            float zz = fast_sigmoid(aZ[mi][r] + biz + bhz);
            float nn = fast_tanh(aI[mi][r] + bin_ + rr * (aH[mi][r] + bhn));
            float hp = first ? x_f32[idx] : bf2f(Hbf[idx]);   // bf16 h-carry for l>=1
            float hv = (1.f - zz) * nn + zz * hp;
            if (last) h_out[idx] = hv;
            Hbf_out[idx] = f2bf(hv);
        }
}

// ---------------- launch ----------------

extern "C" void kernel_launch(void* const* d_in, const int* in_sizes, int n_in,
                              void* d_out, int out_size, void* d_ws, size_t ws_size,
                              hipStream_t stream) {
    const float* x     = (const float*)d_in[0];
    const int*   eidx  = (const int*)d_in[1];
    const float* eattr = (const float*)d_in[2];
    const float* W     = (const float*)d_in[3];
    const float* wih   = (const float*)d_in[4];
    const float* whh   = (const float*)d_in[5];
    const float* bih   = (const float*)d_in[6];
    const float* bhh   = (const float*)d_in[7];
    float* out = (float*)d_out;
    const int* esrc = eidx;
    const int* edst = eidx + NE;

    char* p = (char*)d_ws;
    auto alloc = [&](size_t bytes) -> char* {
        char* r = p; p += (bytes + 255) & ~(size_t)255; return r;
    };
    unsigned short* hbfA  = (unsigned short*)alloc((size_t)NN * DD * 2);
    unsigned short* hbfB  = (unsigned short*)alloc((size_t)NN * DD * 2);
    unsigned short* aggbf = (unsigned short*)alloc((size_t)NN * DD * 2);
    unsigned short* wnb   = (unsigned short*)alloc((size_t)5 * DD * DD * 2);   // W natural, bf16
    unsigned short* wihb  = (unsigned short*)alloc((size_t)768 * DD * 2);      // Wih natural, bf16
    unsigned short* wc5   = (unsigned short*)alloc((size_t)5 * 2 * 768 * 256 * 2);
    int*   degcur = (int*)alloc((size_t)2 * NN * 4);   // deg | cursor (one memset)
    int*   deg    = degcur;
    int*   cursor = degcur + NN;
    int*   basep  = (int*)alloc((size_t)(NN + 1) * 4);
    int*   ssrc   = (int*)alloc((size_t)NE * 4);
    float* sattr  = (float*)alloc((size_t)NE * 4);
    alloc(262144);  // guard slack: padded tile rows (20000..20223) read in-workspace garbage

    hipMemsetAsync(degcur, 0, (size_t)2 * NN * 4, stream);
    prep_kernel<<<6954, 256, 0, stream>>>(x, hbfA, W, wnb, wih, wihb, whh, wc5, edst, deg);
    pgemm_kernel<<<dim3(12, 10), 256, 0, stream>>>(wnb, wihb, wc5);
    scan_kernel<<<1, 1024, 0, stream>>>(deg, basep);
    fill_kernel<<<1250, 256, 0, stream>>>(esrc, edst, eattr, basep, cursor, ssrc, sattr);

    unsigned short* hb_cur = hbfA;
    unsigned short* hb_nxt = hbfB;
    for (int l = 0; l < 5; ++l) {
        gather_agg_kernel<<<5000, 256, 0, stream>>>(hb_cur, basep, ssrc, sattr, aggbf);
        gru4_kernel<<<1264, 512, 0, stream>>>(aggbf, hb_cur, wc5 + (size_t)l * 2 * 768 * 256,
                                              bih, bhh, x, out, hb_nxt,
                                              (l == 0) ? 1 : 0, (l == 4) ? 1 : 0);
        unsigned short* tmp = hb_cur; hb_cur = hb_nxt; hb_nxt = tmp;
    }
    (void)in_sizes; (void)n_in; (void)out_size; (void)ws_size;
}